// Round 9
// baseline (517.996 us; speedup 1.0000x reference)
//
#include <hip/hip_runtime.h>
#include <cstddef>
#include <cstdint>

#define T_LEN 512
#define O_DIM 4

typedef _Float16 f16x8 __attribute__((ext_vector_type(8)));
typedef float    f32x4 __attribute__((ext_vector_type(4)));

#define MFMA(a, b, c) __builtin_amdgcn_mfma_f32_16x16x32_f16((a), (b), (c), 0, 0, 0)

__device__ __forceinline__ float sigm_f(float x) {
    return __builtin_amdgcn_rcpf(1.0f + __builtin_amdgcn_exp2f(x * -1.44269504f));
}
__device__ __forceinline__ float tanh_f(float x) {
    float e = __builtin_amdgcn_exp2f(x * 2.88539008f);
    return __builtin_fmaf(-2.0f, __builtin_amdgcn_rcpf(e + 1.0f), 1.0f);
}

__device__ __forceinline__ f16x8 zf8() {
    f16x8 r;
#pragma unroll
    for (int j = 0; j < 8; ++j) r[j] = (_Float16)0.0f;
    return r;
}

// B-fragment for 16x16x32 f16 MFMA from a row-major [K x 64] fp32 matrix.
__device__ __forceinline__ f16x8 load_bt(const float* __restrict__ W, int k0, int n) {
    const int lane = threadIdx.x & 63;
    const float* p = W + (size_t)(k0 + ((lane >> 4) << 3)) * 64 + n;
    f16x8 r;
#pragma unroll
    for (int j = 0; j < 8; ++j) r[j] = (_Float16)p[(size_t)j * 64];
    return r;
}

// A-fragment from LDS state array [16][72] f16.
__device__ __forceinline__ f16x8 ld_af(const _Float16* base, int kt) {
    const int lane = threadIdx.x & 63;
    const int m = lane & 15, q = lane >> 4;
    return *(const f16x8*)(base + m * 72 + kt * 32 + q * 8);
}

// 256 threads = 4 waves, 4 valid batch rows at tile rows {0,4,8,12}.
// Every segment's post-barrier ds_read window is covered by EARLY fillers
// whose operands were read >=1 segment ago (still live in regs) and whose
// accumulators are fresh or >=1 barrier old:
//   seg1(read sA): early z/r I-terms (nI);      crit w/g A-terms; late z/r A-terms
//   seg2(read nW): early h/a A-terms + phi(sA); crit r W-term;    late z/h W-terms
//   seg3(read hR): early a/ag W-terms (nW)+VALU; crit h rI-term
//   seg4(read nI): early next-w W-terms (nW);   crit a/ag I-terms; late w/g I-terms
// Flush x loads issue at t%16==15 seg1, publish seg4 (slots free after seg3).
__global__ __launch_bounds__(256, 1) void ANIMAZeroExact_86887188398421_kernel(
    const float* __restrict__ x,
    const float* __restrict__ Wenc_w, const float* __restrict__ Wenc_b,
    const float* __restrict__ WfW, const float* __restrict__ WfI, const float* __restrict__ WfA,
    const float* __restrict__ Wg_w, const float* __restrict__ Wg_b,
    const float* __restrict__ Iz_w, const float* __restrict__ Iz_b,
    const float* __restrict__ Ir_w, const float* __restrict__ Ir_b,
    const float* __restrict__ Ih_w, const float* __restrict__ Ih_b,
    const float* __restrict__ AfW, const float* __restrict__ AfI, const float* __restrict__ AfA,
    const float* __restrict__ Ag_w, const float* __restrict__ Ag_b,
    const float* __restrict__ phi_w, const float* __restrict__ phi_b,
    float* __restrict__ out)
{
    __shared__ __align__(16) _Float16 Wl[16][72];
    __shared__ __align__(16) _Float16 Il[16][72];
    __shared__ __align__(16) _Float16 Al[16][72];
    __shared__ __align__(16) _Float16 Rl[16][72];
    __shared__ __align__(16) float xtile[4 * 132 + 4];
    __shared__ __align__(16) float actb[4][16][4];

    const int tid  = threadIdx.x;
    const int w    = tid >> 6;
    const int lane = tid & 63;
    const int q    = lane >> 4;
    const int c    = lane & 15;
    const int n    = w * 16 + c;
    const int r0   = blockIdx.x * 4;

    for (int i = tid; i < 16 * 72; i += 256) {
        (&Wl[0][0])[i] = (_Float16)0.0f; (&Il[0][0])[i] = (_Float16)0.0f;
        (&Al[0][0])[i] = (_Float16)0.0f; (&Rl[0][0])[i] = (_Float16)0.0f;
    }

    // ---- resident weight B-fragments ----
    f16x8 S1B[6], G1B[4], ZB[6], RB[6], HB[6], AB[6], AGB[4], phiB[2];
#pragma unroll
    for (int j = 0; j < 2; ++j) {
        S1B[j] = load_bt(WfW, 32 * j, n);  S1B[2 + j] = load_bt(WfI, 32 * j, n);  S1B[4 + j] = load_bt(WfA, 32 * j, n);
        AB[j]  = load_bt(AfW, 32 * j, n);  AB[2 + j]  = load_bt(AfI, 32 * j, n);  AB[4 + j]  = load_bt(AfA, 32 * j, n);
    }
#pragma unroll
    for (int j = 0; j < 4; ++j) { G1B[j] = load_bt(Wg_w, 32 * j, n); AGB[j] = load_bt(Ag_w, 32 * j, n); }
#pragma unroll
    for (int j = 0; j < 6; ++j) { ZB[j] = load_bt(Iz_w, 32 * j, n); RB[j] = load_bt(Ir_w, 32 * j, n); HB[j] = load_bt(Ih_w, 32 * j, n); }
#pragma unroll
    for (int kt = 0; kt < 2; ++kt)
#pragma unroll
        for (int j = 0; j < 8; ++j) {
            int k = kt * 32 + q * 8 + j;
            phiB[kt][j] = (c < O_DIM) ? (_Float16)phi_w[k * O_DIM + c] : (_Float16)0.0f;
        }

    float We[8];
#pragma unroll
    for (int j = 0; j < 8; ++j) We[j] = Wenc_w[j * 64 + n];

    const float bias_g  = Wg_b[n],  bias_z = Iz_b[n], bias_r = Ir_b[n];
    const float bias_h  = Ih_b[n],  bias_ag = Ag_b[n], bias_e = Wenc_b[n];
    const float bias_p  = (c < O_DIM) ? phi_b[c] : 0.0f;

    f32x4 zero4 = {0.f, 0.f, 0.f, 0.f};

    // prologue: stage x-tile slots su = x(1+su); xt(0) direct
    if (tid < 64) {
        const int row = tid >> 4, su = tid & 15;
        const float* xg = x + (size_t)(r0 + row) * (T_LEN * 8) + (1 + su) * 8;
        float4 a = *(const float4*)(xg);
        float4 b = *(const float4*)(xg + 4);
        float* d = &xtile[row * 132 + su * 8];
        *(float4*)d = a; *(float4*)(d + 4) = b;
    }
    float xt;
    {
        const float* xg = x + (size_t)(r0 + q) * (T_LEN * 8);
        float4 a = *(const float4*)(xg);
        float4 b = *(const float4*)(xg + 4);
        float d = bias_e;
        d = __builtin_fmaf(a.x, We[0], d); d = __builtin_fmaf(a.y, We[1], d);
        d = __builtin_fmaf(a.z, We[2], d); d = __builtin_fmaf(a.w, We[3], d);
        d = __builtin_fmaf(b.x, We[4], d); d = __builtin_fmaf(b.y, We[5], d);
        d = __builtin_fmaf(b.z, We[6], d); d = __builtin_fmaf(b.w, We[7], d);
        xt = tanh_f(d);
    }

    // loop-carried (zero-init == states(-1)=0 contributions)
    f16x8 nI0 = zf8(), nI1 = zf8(), nW0 = zf8(), nW1 = zf8();
    f32x4 w_a = zero4, w_b = zero4, g_a = zero4, g_b = zero4;
    f32x4 zp_a, zp_c, rp_a, rp_c, hp_a, hp_c, ap_a, ap_c, ag_a, ag_c;
    float Iv = 0.f;

    __syncthreads();

#pragma unroll 1
    for (int t = 0; t < T_LEN; ++t) {
        const bool fl = ((t & 15) == 0) && (t > 0);   // flush stored actions
        const bool pf = ((t & 15) == 15);             // prefetch next x period

        // ============ seg1: W_new ============
        f16x8 sA0 = ld_af(&Al[0][0], 0), sA1 = ld_af(&Al[0][0], 1);
        float4 xla = {0,0,0,0}, xlb = {0,0,0,0};
        if (pf && tid < 64) {
            const int row = tid >> 4, su = tid & 15;
            int off = (t + 2 + su) * 8;
            if (off > T_LEN * 8 - 8) off = T_LEN * 8 - 8;
            const float* xg = x + (size_t)(r0 + row) * (T_LEN * 8) + off;
            xla = *(const float4*)(xg); xlb = *(const float4*)(xg + 4);
        }
        // early fillers: z/r I-terms (operand nI read prev seg4; fresh accums)
        zp_a = MFMA(nI0, ZB[2], zero4); zp_c = MFMA(nI1, ZB[3], zero4);
        rp_a = MFMA(nI0, RB[2], zero4); rp_c = MFMA(nI1, RB[3], zero4);
        // critical: w/g A-terms (accums last touched prev seg4-late)
        w_a = MFMA(sA0, S1B[4], w_a);  g_a = MFMA(sA0, G1B[2], g_a);
        w_b = MFMA(sA1, S1B[5], w_b);  g_b = MFMA(sA1, G1B[3], g_b);
        {
            float wn = tanh_f(xt + w_a[0] + w_b[0]) * sigm_f(g_a[0] + g_b[0] + bias_g);
            Wl[4 * q][n] = (_Float16)wn;
        }
        // late fillers: z/r A-terms (r accum ready for seg2 critical after alpha)
        zp_a = MFMA(sA0, ZB[4], zp_a);  zp_c = MFMA(sA1, ZB[5], zp_c);
        rp_a = MFMA(sA0, RB[4], rp_a);  rp_c = MFMA(sA1, RB[5], rp_c);
        __syncthreads();  // alpha

        // ============ seg2: r*I ============
        f16x8 tW0 = ld_af(&Wl[0][0], 0), tW1 = ld_af(&Wl[0][0], 1);
        // early fillers: h/a A-terms + phi (operand sA read seg1; fresh accums)
        hp_a = MFMA(sA0, HB[4], zero4); hp_c = MFMA(sA1, HB[5], zero4);
        ap_a = MFMA(sA0, AB[4], zero4); ap_c = MFMA(sA1, AB[5], zero4);
        if (w == (t & 3)) {   // rotating action(t-1)
            f32x4 act = MFMA(sA0, phiB[0], zero4);
            act = MFMA(sA1, phiB[1], act);
            if (t > 0 && c < O_DIM)
                actb[q][(t - 1) & 15][c] = act[0] + bias_p;
        }
        // critical: r W-term (rp last touched seg1-late, 1 barrier ago)
        rp_a = MFMA(tW0, RB[0], rp_a);  rp_c = MFMA(tW1, RB[1], rp_c);
        {
            float rv = sigm_f(rp_a[0] + rp_c[0] + bias_r);
            Rl[4 * q][n] = (_Float16)(rv * Iv);
        }
        // late fillers: z/h W-terms
        zp_a = MFMA(tW0, ZB[0], zp_a);  zp_c = MFMA(tW1, ZB[1], zp_c);
        hp_a = MFMA(tW0, HB[0], hp_a);  hp_c = MFMA(tW1, HB[1], hp_c);
        nW0 = tW0; nW1 = tW1;
        __syncthreads();  // beta

        // ============ seg3: I_new ============
        f16x8 hR0 = ld_af(&Rl[0][0], 0), hR1 = ld_af(&Rl[0][0], 1);
        // early fillers: a/ag W-terms (operand nW read seg2) + VALU
        ap_a = MFMA(nW0, AB[0], ap_a);  ap_c = MFMA(nW1, AB[1], ap_c);
        ag_a = MFMA(nW0, AGB[0], zero4); ag_c = MFMA(nW1, AGB[1], zero4);
        float zv = sigm_f(zp_a[0] + zp_c[0] + bias_z);
        const float* xs = &xtile[q * 132 + (t & 15) * 8];
        float4 qa = *(const float4*)xs;
        float4 qb = *(const float4*)(xs + 4);
        float xtn;
        {
            float d = bias_e;
            d = __builtin_fmaf(qa.x, We[0], d); d = __builtin_fmaf(qa.y, We[1], d);
            d = __builtin_fmaf(qa.z, We[2], d); d = __builtin_fmaf(qa.w, We[3], d);
            d = __builtin_fmaf(qb.x, We[4], d); d = __builtin_fmaf(qb.y, We[5], d);
            d = __builtin_fmaf(qb.z, We[6], d); d = __builtin_fmaf(qb.w, We[7], d);
            xtn = tanh_f(d);
        }
        if (fl && tid < 64) {
            const int row = tid >> 4, sl = tid & 15;
            float4 av = *(const float4*)(&actb[row][sl][0]);
            *(float4*)(out + (size_t)(r0 + row) * (T_LEN * O_DIM) + (t - 16 + sl) * 4) = av;
        }
        // critical: h rI-term (hp last touched seg2-late, 1 barrier ago)
        hp_a = MFMA(hR0, HB[2], hp_a);  hp_c = MFMA(hR1, HB[3], hp_c);
        {
            float hv = tanh_f(hp_a[0] + hp_c[0] + bias_h);
            Iv = __builtin_fmaf(zv, hv - Iv, Iv);
            Il[4 * q][n] = (_Float16)Iv;
        }
        __syncthreads();  // gamma

        // ============ seg4: A_new ============
        f16x8 tI0 = ld_af(&Il[0][0], 0), tI1 = ld_af(&Il[0][0], 1);
        // early fillers: next step's w W-terms (operand nW read seg2; fresh accums)
        w_a = MFMA(nW0, S1B[0], zero4); w_b = MFMA(nW1, S1B[1], zero4);
        // critical: a/ag I-terms (ap last touched seg3-early, ag seg3-early)
        ap_a = MFMA(tI0, AB[2], ap_a);  ap_c = MFMA(tI1, AB[3], ap_c);
        ag_a = MFMA(tI0, AGB[2], ag_a); ag_c = MFMA(tI1, AGB[3], ag_c);
        {
            float av = tanh_f(ap_a[0] + ap_c[0]) * sigm_f(ag_a[0] + ag_c[0] + bias_ag);
            Al[4 * q][n] = (_Float16)av;
        }
        // late fillers: w/g I-terms (feed seg1 criticals across delta)
        w_a = MFMA(tI0, S1B[2], w_a);   w_b = MFMA(tI1, S1B[3], w_b);
        g_a = MFMA(tI0, G1B[0], zero4); g_b = MFMA(tI1, G1B[1], zero4);
        if (pf && tid < 64) {
            const int row = tid >> 4, su = tid & 15;
            float* d = &xtile[row * 132 + su * 8];
            *(float4*)d = xla; *(float4*)(d + 4) = xlb;
        }
        nI0 = tI0; nI1 = tI1;
        xt = xtn;
        __syncthreads();  // delta
    }

    // epilogue: action(511) + final flush (496..511)
    {
        f16x8 eA0 = ld_af(&Al[0][0], 0), eA1 = ld_af(&Al[0][0], 1);
        if (w == 0) {
            f32x4 act = MFMA(eA0, phiB[0], zero4);
            act = MFMA(eA1, phiB[1], act);
            if (c < O_DIM)
                actb[q][15][c] = act[0] + bias_p;
        }
        __syncthreads();
        if (tid < 64) {
            const int row = tid >> 4, sl = tid & 15;
            float4 av = *(const float4*)(&actb[row][sl][0]);
            *(float4*)(out + (size_t)(r0 + row) * (T_LEN * O_DIM) + (496 + sl) * 4) = av;
        }
    }
}

extern "C" void kernel_launch(void* const* d_in, const int* in_sizes, int n_in,
                              void* d_out, int out_size, void* d_ws, size_t ws_size,
                              hipStream_t stream) {
    ANIMAZeroExact_86887188398421_kernel<<<dim3(256), dim3(256), 0, stream>>>(
        (const float*)d_in[0],
        (const float*)d_in[1],  (const float*)d_in[2],
        (const float*)d_in[3],  (const float*)d_in[4],  (const float*)d_in[5],
        (const float*)d_in[6],  (const float*)d_in[7],
        (const float*)d_in[8],  (const float*)d_in[9],
        (const float*)d_in[10], (const float*)d_in[11],
        (const float*)d_in[12], (const float*)d_in[13],
        (const float*)d_in[14], (const float*)d_in[15], (const float*)d_in[16],
        (const float*)d_in[17], (const float*)d_in[18],
        (const float*)d_in[19], (const float*)d_in[20],
        (float*)d_out);
}